// Round 14
// baseline (119.487 us; speedup 1.0000x reference)
//
#include <hip/hip_runtime.h>
#include <hip/hip_bf16.h>

// EdgeNet fused 2-layer MLP, MI355X (gfx950) — round 13.
//
// out[m][n2] = relu( W2 · relu( W1' · child[m] + b1 ) + b2 ),  W1' = W1 ⊙ parent
//
// R12 (single lgkm-only barrier, xf/hf both double-buffered): 104 us. Gap vs
// 5.2 us/tile HBM floor traced to prefetch flight time: load_rows(t+1) issued
// at loop top but consumed by stage() in the SAME iteration (~2 us of cover vs
// full-contention HBM latency). R13:
//   * issue load_rows(t+2) immediately AFTER stage(p^1) frees c -> loads are
//     in flight across BAR + L2 + store + next L1 + next pack (~full tile).
//   * plain stores (R12's nontemporal cost +25 MB WRITE amplification).
//
// Per-iter schedule (xf[p] = x(t), c = rows(t+1) on entry):
//   (2) L1: xf[p] -> acc1
//   (3) relu/pack acc1 -> hf[p]
//   (4) stage: cvt c -> xf[p^1]            (x(t+1))
//   (4.5) load_rows(t+2) -> c              (full-tile flight)
//   (5) BAR: s_waitcnt lgkmcnt(0); s_barrier   (vmem NOT drained)
//   (6) L2: hf[p] -> acc2; store out(t)
// Hazard args as R12 (all cross-wave orderings pass through one barrier).
//
// MFMA conventions (verified R1..R12, absmax 0.03125):
//   A-frag: lane holds A[row = lane&15][k = 8*(lane>>4)+i], i=0..7
//   B-frag: lane holds B[k = 8*(lane>>4)+i][col = lane&15]
//   C/D  : lane holds C[row = 4*(lane>>4)+reg][col = lane&15]

typedef float f32x4 __attribute__((ext_vector_type(4)));
typedef short bf16x8 __attribute__((ext_vector_type(8)));
typedef unsigned int u32;
typedef u32 u32x4 __attribute__((ext_vector_type(4)));

#define BARRIER_LGKM() asm volatile("s_waitcnt lgkmcnt(0)\n\ts_barrier" ::: "memory")

__device__ __forceinline__ u32 pk2bf(float a, float b) {
    __hip_bfloat162 h2 = __float22bfloat162_rn(make_float2(a, b));
    u32 r;
    __builtin_memcpy(&r, &h2, 4);
    return r;
}

// Pack weights into per-lane MFMA A-fragment order; parent folded into W1.
// halfword[((kt*16 + nt)*64 + lane)*8 + i] = bf16(W'[nt*16 + (lane&15)][kt*32 + 8*(lane>>4) + i])
__global__ __launch_bounds__(256) void pack_w_kernel(
    const float* __restrict__ W1, const float* __restrict__ W2,
    const float* __restrict__ parent, unsigned short* __restrict__ wp)
{
    int t = blockIdx.x * 256 + threadIdx.x;   // 0..16383
    int sel = t >> 13;
    int tt = t & 8191;
    int lane = tt & 63;
    int nt = (tt >> 6) & 15;
    int kt = tt >> 10;
    int n = nt * 16 + (lane & 15);
    int k0 = kt * 32 + 8 * (lane >> 4);
    const float* W = sel ? W2 : W1;
    const float* src = W + n * 256 + k0;
    f32x4 a = *(const f32x4*)src;
    f32x4 b = *(const f32x4*)(src + 4);
    if (sel == 0) {                            // fold parent into W1
        a *= *(const f32x4*)(parent + k0);
        b *= *(const f32x4*)(parent + k0 + 4);
    }
    u32x4 d;
    d.x = pk2bf(a.x, a.y);
    d.y = pk2bf(a.z, a.w);
    d.z = pk2bf(b.x, b.y);
    d.w = pk2bf(b.z, b.w);
    *(u32x4*)(wp + (size_t)t * 8) = d;
}

__global__ __launch_bounds__(512, 2) void fused_mlp(
    const float* __restrict__ child,
    const float* __restrict__ b1, const float* __restrict__ b2,
    const unsigned short* __restrict__ w1p, const unsigned short* __restrict__ w2p,
    float* __restrict__ out, int n_rows)
{
    // frags: frag (mf, kt) at halfword (mf*8+kt)*512 + lane*8   (mf<4, kt<8)
    __shared__ __align__(16) unsigned short xf[2][16384];  // 2 x 32 KiB x-frags
    __shared__ __align__(16) unsigned short hf[2][16384];  // 2 x 32 KiB h-frags
    __shared__ __align__(16) float bias[512];              // [0..255]=b1, [256..511]=b2

    const int tid = threadIdx.x;
    const int lane = tid & 63;
    const int w = tid >> 6;        // wave 0..7; owns cols [32w, 32w+32) both layers
    const int m16 = lane & 15;
    const int g = lane >> 4;
    const int mfS = w >> 1;        // stage role: rows [16*mfS, +16)
    const int khalf = (w & 1) * 128;

    if (tid < 256) bias[tid] = b1[tid];
    else           bias[tid] = b2[tid - 256];

    const int n_tiles = (n_rows + 63) >> 6;    // 3125 (200000 = 64*3125)

    // transient-held child rows (32 VGPRs); clamped index makes any tile safe
    f32x4 c[8];
    auto load_rows = [&](int tile) {
        long row = (long)tile * 64 + mfS * 16 + m16;
        long lim = (long)n_rows - 1;
        if (row > lim) row = lim;              // clamp: harmless duplicate reads
        const float* cp = child + row * 256 + khalf + 8 * g;
        #pragma unroll
        for (int kt = 0; kt < 4; ++kt) {
            c[2 * kt]     = *(const f32x4*)(cp + kt * 32);
            c[2 * kt + 1] = *(const f32x4*)(cp + kt * 32 + 4);
        }
    };
    auto stage = [&](int buf) {                // cvt held regs -> x-frags
        #pragma unroll
        for (int kt = 0; kt < 4; ++kt) {
            u32x4 u;
            u.x = pk2bf(c[2 * kt].x, c[2 * kt].y);
            u.y = pk2bf(c[2 * kt].z, c[2 * kt].w);
            u.z = pk2bf(c[2 * kt + 1].x, c[2 * kt + 1].y);
            u.w = pk2bf(c[2 * kt + 1].z, c[2 * kt + 1].w);
            *(u32x4*)&xf[buf][((mfS * 8 + (w & 1) * 4 + kt) * 64 + lane) * 8] = u;
        }
    };

    // prologue: xf[0] = x(t0); c = rows(t0 + G)
    load_rows(blockIdx.x);
    stage(0);
    load_rows(blockIdx.x + gridDim.x);
    BARRIER_LGKM();                            // bias + xf[0] ready

    int p = 0;
    for (int tile = blockIdx.x; tile < n_tiles; tile += gridDim.x) {
        const int row0 = tile * 64;

        // (2) layer 1: acc1[j][mf] over xf[p]
        f32x4 acc1[2][4];
        #pragma unroll
        for (int j = 0; j < 2; ++j) {
            f32x4 bv = *(const f32x4*)&bias[(2 * w + j) * 16 + 4 * g];
            #pragma unroll
            for (int mf = 0; mf < 4; ++mf) acc1[j][mf] = bv;
        }
        #pragma unroll
        for (int kt = 0; kt < 8; ++kt) {
            bf16x8 a0 = *(const bf16x8*)(w1p + (size_t)((kt * 16 + 2 * w) * 64 + lane) * 8);
            bf16x8 a1 = *(const bf16x8*)(w1p + (size_t)((kt * 16 + 2 * w + 1) * 64 + lane) * 8);
            #pragma unroll
            for (int mf = 0; mf < 4; ++mf) {
                bf16x8 bfrag = *(const bf16x8*)&xf[p][((mf * 8 + kt) * 64 + lane) * 8];
                acc1[0][mf] = __builtin_amdgcn_mfma_f32_16x16x32_bf16(a0, bfrag, acc1[0][mf], 0, 0, 0);
                acc1[1][mf] = __builtin_amdgcn_mfma_f32_16x16x32_bf16(a1, bfrag, acc1[1][mf], 0, 0, 0);
            }
        }

        // (3) relu + pack h -> hf[p]  (kt2 = w)
        // lane holds h[k2 = 32w + 16j + 4g + r][m = mf*16 + m16]
        //   -> frag (mf, w), lane' = 16*(2j + (g>>1)) + m16, halfword 4*(g&1) + r
        #pragma unroll
        for (int j = 0; j < 2; ++j) {
            #pragma unroll
            for (int mf = 0; mf < 4; ++mf) {
                f32x4 v = acc1[j][mf];
                v.x = fmaxf(v.x, 0.0f); v.y = fmaxf(v.y, 0.0f);
                v.z = fmaxf(v.z, 0.0f); v.w = fmaxf(v.w, 0.0f);
                u32* dst = (u32*)&hf[p][((mf * 8 + w) * 64 + 16 * (2 * j + (g >> 1)) + m16) * 8 + 4 * (g & 1)];
                dst[0] = pk2bf(v.x, v.y);
                dst[1] = pk2bf(v.z, v.w);
            }
        }

        // (4) stage x(t+1) into xf[p^1]; (4.5) reload c with rows(t+2)
        stage(p ^ 1);
        load_rows(tile + 2 * gridDim.x);       // full-tile flight (clamped)

        // (5) the ONLY barrier: LDS ordering, vmem stays in flight
        BARRIER_LGKM();

        // (6) layer 2 over hf[p] + store out(t)
        f32x4 acc2[2][4];
        #pragma unroll
        for (int j = 0; j < 2; ++j) {
            f32x4 bv = *(const f32x4*)&bias[256 + (2 * w + j) * 16 + 4 * g];
            #pragma unroll
            for (int mf = 0; mf < 4; ++mf) acc2[j][mf] = bv;
        }
        #pragma unroll
        for (int kt = 0; kt < 8; ++kt) {
            bf16x8 a0 = *(const bf16x8*)(w2p + (size_t)((kt * 16 + 2 * w) * 64 + lane) * 8);
            bf16x8 a1 = *(const bf16x8*)(w2p + (size_t)((kt * 16 + 2 * w + 1) * 64 + lane) * 8);
            #pragma unroll
            for (int mf = 0; mf < 4; ++mf) {
                bf16x8 hfrag = *(const bf16x8*)&hf[p][((mf * 8 + kt) * 64 + lane) * 8];
                acc2[0][mf] = __builtin_amdgcn_mfma_f32_16x16x32_bf16(a0, hfrag, acc2[0][mf], 0, 0, 0);
                acc2[1][mf] = __builtin_amdgcn_mfma_f32_16x16x32_bf16(a1, hfrag, acc2[1][mf], 0, 0, 0);
            }
        }

        // store: lane holds out[m = mf*16+m16][n2 = (2w+j)*16 + 4g + r]
        #pragma unroll
        for (int mf = 0; mf < 4; ++mf) {
            if (row0 + mf * 16 < n_rows) {     // wave-uniform
                float* orow = out + (size_t)(row0 + mf * 16 + m16) * 256 + 4 * g;
                #pragma unroll
                for (int j = 0; j < 2; ++j) {
                    f32x4 v = acc2[j][mf];
                    v.x = fmaxf(v.x, 0.0f); v.y = fmaxf(v.y, 0.0f);
                    v.z = fmaxf(v.z, 0.0f); v.w = fmaxf(v.w, 0.0f);
                    *(f32x4*)(orow + (2 * w + j) * 16) = v;
                }
            }
        }

        p ^= 1;
    }
}

extern "C" void kernel_launch(void* const* d_in, const int* in_sizes, int n_in,
                              void* d_out, int out_size, void* d_ws, size_t ws_size,
                              hipStream_t stream) {
    const float* parent = (const float*)d_in[0];
    const float* child  = (const float*)d_in[1];
    const float* W1     = (const float*)d_in[2];
    const float* b1     = (const float*)d_in[3];
    const float* W2     = (const float*)d_in[4];
    const float* b2     = (const float*)d_in[5];
    float* out = (float*)d_out;

    unsigned short* wp = (unsigned short*)d_ws;   // [0..65535]=W1' frags, [65536..131071]=W2 frags
    const int n_rows = in_sizes[1] / 256;         // 200000

    pack_w_kernel<<<64, 256, 0, stream>>>(W1, W2, parent, wp);
    fused_mlp<<<256, 512, 0, stream>>>(child, b1, b2,
                                       wp, wp + 65536, out, n_rows);
}

// Round 15
// 101.750 us; speedup vs baseline: 1.1743x; 1.1743x over previous
//
#include <hip/hip_runtime.h>
#include <hip/hip_bf16.h>

// EdgeNet fused 2-layer MLP, MI355X (gfx950) — round 14.
//
// out[m][n2] = relu( W2 · relu( W1' · child[m] + b1 ) + b2 ),  W1' = W1 ⊙ parent
//
// R12 (single lgkm barrier, dbuf xf/hf) = 104 us best. R13 (deeper prefetch)
// = 119 us: holding c across the barrier/L2 hurt — reverted.
// R14: remaining per-tile latency chain = weight-frag loads from L2 (2x16 per
// wave per tile, ~200-400 cyc each; compiler rematerializes instead of keeping
// resident — R8 evidence). Fix: load all 32 weight frags ONCE and PIN them
// with asm volatile("" : "+v") — opaque output, cannot be rematerialized, so
// the allocator must keep ~210 regs (fits 256 cap of launch_bounds(512,2)).
// Steady-state loop has ZERO global loads except child rows.
//
// Schedule per tile (identical to R12):
//   (1) load_rows(t+1) -> c     (2) L1: xf[p] -> acc1   (3) relu/pack -> hf[p]
//   (4) stage c -> xf[p^1]      (5) lgkm-only barrier    (6) L2 + store
//
// MFMA conventions (verified R1..R13, absmax 0.03125):
//   A-frag: lane holds A[row = lane&15][k = 8*(lane>>4)+i], i=0..7
//   B-frag: lane holds B[k = 8*(lane>>4)+i][col = lane&15]
//   C/D  : lane holds C[row = 4*(lane>>4)+reg][col = lane&15]

typedef float f32x4 __attribute__((ext_vector_type(4)));
typedef short bf16x8 __attribute__((ext_vector_type(8)));
typedef unsigned int u32;
typedef u32 u32x4 __attribute__((ext_vector_type(4)));

#define BARRIER_LGKM() asm volatile("s_waitcnt lgkmcnt(0)\n\ts_barrier" ::: "memory")

__device__ __forceinline__ u32 pk2bf(float a, float b) {
    __hip_bfloat162 h2 = __float22bfloat162_rn(make_float2(a, b));
    u32 r;
    __builtin_memcpy(&r, &h2, 4);
    return r;
}

// Pack weights into per-lane MFMA A-fragment order; parent folded into W1.
// halfword[((kt*16 + nt)*64 + lane)*8 + i] = bf16(W'[nt*16 + (lane&15)][kt*32 + 8*(lane>>4) + i])
__global__ __launch_bounds__(256) void pack_w_kernel(
    const float* __restrict__ W1, const float* __restrict__ W2,
    const float* __restrict__ parent, unsigned short* __restrict__ wp)
{
    int t = blockIdx.x * 256 + threadIdx.x;   // 0..16383
    int sel = t >> 13;
    int tt = t & 8191;
    int lane = tt & 63;
    int nt = (tt >> 6) & 15;
    int kt = tt >> 10;
    int n = nt * 16 + (lane & 15);
    int k0 = kt * 32 + 8 * (lane >> 4);
    const float* W = sel ? W2 : W1;
    const float* src = W + n * 256 + k0;
    f32x4 a = *(const f32x4*)src;
    f32x4 b = *(const f32x4*)(src + 4);
    if (sel == 0) {                            // fold parent into W1
        a *= *(const f32x4*)(parent + k0);
        b *= *(const f32x4*)(parent + k0 + 4);
    }
    u32x4 d;
    d.x = pk2bf(a.x, a.y);
    d.y = pk2bf(a.z, a.w);
    d.z = pk2bf(b.x, b.y);
    d.w = pk2bf(b.z, b.w);
    *(u32x4*)(wp + (size_t)t * 8) = d;
}

__global__ __launch_bounds__(512, 2) void fused_mlp(
    const float* __restrict__ child,
    const float* __restrict__ b1, const float* __restrict__ b2,
    const unsigned short* __restrict__ w1p, const unsigned short* __restrict__ w2p,
    float* __restrict__ out, int n_rows)
{
    // frags: frag (mf, kt) at halfword (mf*8+kt)*512 + lane*8   (mf<4, kt<8)
    __shared__ __align__(16) unsigned short xf[2][16384];  // 2 x 32 KiB x-frags
    __shared__ __align__(16) unsigned short hf[2][16384];  // 2 x 32 KiB h-frags
    __shared__ __align__(16) float bias[512];              // [0..255]=b1, [256..511]=b2

    const int tid = threadIdx.x;
    const int lane = tid & 63;
    const int w = tid >> 6;        // wave 0..7; owns cols [32w, 32w+32) both layers
    const int m16 = lane & 15;
    const int g = lane >> 4;
    const int mfS = w >> 1;        // stage role: rows [16*mfS, +16)
    const int khalf = (w & 1) * 128;

    if (tid < 256) bias[tid] = b1[tid];
    else           bias[tid] = b2[tid - 256];

    // ---- load this wave's weight fragments ONCE, then PIN in registers ----
    bf16x8 wA1[2][8], wA2[2][8];
    #pragma unroll
    for (int ntl = 0; ntl < 2; ++ntl) {
        #pragma unroll
        for (int kt = 0; kt < 8; ++kt) {
            wA1[ntl][kt] = *(const bf16x8*)(w1p + (size_t)((kt * 16 + 2 * w + ntl) * 64 + lane) * 8);
            wA2[ntl][kt] = *(const bf16x8*)(w2p + (size_t)((kt * 16 + 2 * w + ntl) * 64 + lane) * 8);
        }
    }
    #pragma unroll
    for (int ntl = 0; ntl < 2; ++ntl) {
        #pragma unroll
        for (int kt = 0; kt < 8; ++kt) {
            asm volatile("" : "+v"(wA1[ntl][kt]));   // opaque: cannot rematerialize
            asm volatile("" : "+v"(wA2[ntl][kt]));
        }
    }

    const int n_tiles = (n_rows + 63) >> 6;    // 3125 (200000 = 64*3125)

    // transient-held child rows for the NEXT tile (32 VGPRs)
    f32x4 c[8];
    auto load_rows = [&](int tile) {
        long row = (long)tile * 64 + mfS * 16 + m16;
        long lim = (long)n_rows - 1;
        if (row > lim) row = lim;              // clamp: harmless duplicate reads
        const float* cp = child + row * 256 + khalf + 8 * g;
        #pragma unroll
        for (int kt = 0; kt < 4; ++kt) {
            c[2 * kt]     = *(const f32x4*)(cp + kt * 32);
            c[2 * kt + 1] = *(const f32x4*)(cp + kt * 32 + 4);
        }
    };
    auto stage = [&](int buf) {                // cvt held regs -> x-frags
        #pragma unroll
        for (int kt = 0; kt < 4; ++kt) {
            u32x4 u;
            u.x = pk2bf(c[2 * kt].x, c[2 * kt].y);
            u.y = pk2bf(c[2 * kt].z, c[2 * kt].w);
            u.z = pk2bf(c[2 * kt + 1].x, c[2 * kt + 1].y);
            u.w = pk2bf(c[2 * kt + 1].z, c[2 * kt + 1].w);
            *(u32x4*)&xf[buf][((mfS * 8 + (w & 1) * 4 + kt) * 64 + lane) * 8] = u;
        }
    };

    // prologue: stage first tile into xf[0]
    load_rows(blockIdx.x);
    stage(0);
    BARRIER_LGKM();                            // bias + xf[0] ready

    int p = 0;
    for (int tile = blockIdx.x; tile < n_tiles; tile += gridDim.x) {
        const int row0 = tile * 64;
        const int nxt = tile + gridDim.x;
        const bool have_nxt = nxt < n_tiles;   // block-uniform

        // (1) issue next tile's child loads — in flight through layer 1
        if (have_nxt) load_rows(nxt);

        // (2) layer 1: acc1[j][mf] over xf[p] — weights already in registers
        f32x4 acc1[2][4];
        #pragma unroll
        for (int j = 0; j < 2; ++j) {
            f32x4 bv = *(const f32x4*)&bias[(2 * w + j) * 16 + 4 * g];
            #pragma unroll
            for (int mf = 0; mf < 4; ++mf) acc1[j][mf] = bv;
        }
        #pragma unroll
        for (int kt = 0; kt < 8; ++kt) {
            #pragma unroll
            for (int mf = 0; mf < 4; ++mf) {
                bf16x8 bfrag = *(const bf16x8*)&xf[p][((mf * 8 + kt) * 64 + lane) * 8];
                acc1[0][mf] = __builtin_amdgcn_mfma_f32_16x16x32_bf16(wA1[0][kt], bfrag, acc1[0][mf], 0, 0, 0);
                acc1[1][mf] = __builtin_amdgcn_mfma_f32_16x16x32_bf16(wA1[1][kt], bfrag, acc1[1][mf], 0, 0, 0);
            }
        }

        // (3) relu + pack h -> hf[p]  (kt2 = w)
        // lane holds h[k2 = 32w + 16j + 4g + r][m = mf*16 + m16]
        //   -> frag (mf, w), lane' = 16*(2j + (g>>1)) + m16, halfword 4*(g&1) + r
        #pragma unroll
        for (int j = 0; j < 2; ++j) {
            #pragma unroll
            for (int mf = 0; mf < 4; ++mf) {
                f32x4 v = acc1[j][mf];
                v.x = fmaxf(v.x, 0.0f); v.y = fmaxf(v.y, 0.0f);
                v.z = fmaxf(v.z, 0.0f); v.w = fmaxf(v.w, 0.0f);
                u32* dst = (u32*)&hf[p][((mf * 8 + w) * 64 + 16 * (2 * j + (g >> 1)) + m16) * 8 + 4 * (g & 1)];
                dst[0] = pk2bf(v.x, v.y);
                dst[1] = pk2bf(v.z, v.w);
            }
        }

        // (4) stage next tile's x-frags into xf[p^1]
        if (have_nxt) stage(p ^ 1);

        // (5) the ONLY barrier: LDS ordering, vmem stays in flight
        BARRIER_LGKM();

        // (6) layer 2 over hf[p] + store out(t) — weights already in registers
        f32x4 acc2[2][4];
        #pragma unroll
        for (int j = 0; j < 2; ++j) {
            f32x4 bv = *(const f32x4*)&bias[256 + (2 * w + j) * 16 + 4 * g];
            #pragma unroll
            for (int mf = 0; mf < 4; ++mf) acc2[j][mf] = bv;
        }
        #pragma unroll
        for (int kt = 0; kt < 8; ++kt) {
            #pragma unroll
            for (int mf = 0; mf < 4; ++mf) {
                bf16x8 hfrag = *(const bf16x8*)&hf[p][((mf * 8 + kt) * 64 + lane) * 8];
                acc2[0][mf] = __builtin_amdgcn_mfma_f32_16x16x32_bf16(wA2[0][kt], hfrag, acc2[0][mf], 0, 0, 0);
                acc2[1][mf] = __builtin_amdgcn_mfma_f32_16x16x32_bf16(wA2[1][kt], hfrag, acc2[1][mf], 0, 0, 0);
            }
        }

        // store: lane holds out[m = mf*16+m16][n2 = (2w+j)*16 + 4g + r]
        #pragma unroll
        for (int mf = 0; mf < 4; ++mf) {
            if (row0 + mf * 16 < n_rows) {     // wave-uniform
                float* orow = out + (size_t)(row0 + mf * 16 + m16) * 256 + 4 * g;
                #pragma unroll
                for (int j = 0; j < 2; ++j) {
                    f32x4 v = acc2[j][mf];
                    v.x = fmaxf(v.x, 0.0f); v.y = fmaxf(v.y, 0.0f);
                    v.z = fmaxf(v.z, 0.0f); v.w = fmaxf(v.w, 0.0f);
                    *(f32x4*)(orow + (2 * w + j) * 16) = v;
                }
            }
        }

        p ^= 1;
    }
}

extern "C" void kernel_launch(void* const* d_in, const int* in_sizes, int n_in,
                              void* d_out, int out_size, void* d_ws, size_t ws_size,
                              hipStream_t stream) {
    const float* parent = (const float*)d_in[0];
    const float* child  = (const float*)d_in[1];
    const float* W1     = (const float*)d_in[2];
    const float* b1     = (const float*)d_in[3];
    const float* W2     = (const float*)d_in[4];
    const float* b2     = (const float*)d_in[5];
    float* out = (float*)d_out;

    unsigned short* wp = (unsigned short*)d_ws;   // [0..65535]=W1' frags, [65536..131071]=W2 frags
    const int n_rows = in_sizes[1] / 256;         // 200000

    pack_w_kernel<<<64, 256, 0, stream>>>(W1, W2, parent, wp);
    fused_mlp<<<256, 512, 0, stream>>>(child, b1, b2,
                                       wp, wp + 65536, out, n_rows);
}